// Round 1
// baseline (733.799 us; speedup 1.0000x reference)
//
#include <hip/hip_runtime.h>

// ---------------------------------------------------------------------------
// MonarchTransformer on MI355X (gfx950)
// Pipeline: k_prep -> k_stage1 (fused monarch+LN+rope+wQ->f1,f2,V) -> k_kv ->
//           k_kvt -> k_out (O = f1 @ kv, write-bound)
// ---------------------------------------------------------------------------

using bf16x8 = __attribute__((ext_vector_type(8))) short;
using f32x4  = __attribute__((ext_vector_type(4))) float;
using f32x16 = __attribute__((ext_vector_type(16))) float;
typedef unsigned short u16;
typedef unsigned int   u32;

#define MFMA16(a,b,c) __builtin_amdgcn_mfma_f32_16x16x32_bf16((a),(b),(c),0,0,0)
#define MFMA32(a,b,c) __builtin_amdgcn_mfma_f32_32x32x16_bf16((a),(b),(c),0,0,0)

__device__ __forceinline__ u16 f2b(float x){
  u32 u = __builtin_bit_cast(u32, x);
  return (u16)((u + 0x7FFFu + ((u >> 16) & 1u)) >> 16);   // RNE f32->bf16
}
__device__ __forceinline__ float b2f(u16 h){
  u32 u = ((u32)h) << 16;
  return __builtin_bit_cast(float, u);
}

// constants
#define DC_ 2.821109907456e-4f      /* 0.6^16 */
#define BC_ 0.7745966692414834f     /* sqrt(0.6) */

// workspace layout (bytes)
constexpr size_t OFF_LT  = 0;                     // Lt  [32][64][64] bf16   262144
constexpr size_t OFF_RT  = OFF_LT + 262144;       // Rt  [64][32][32] bf16   131072
constexpr size_t OFF_WB  = OFF_RT + 131072;       // Wb  [128][64]    bf16    16384
constexpr size_t OFF_KV  = OFF_WB + 16384;        // kv  [128][960]   f32    491520
constexpr size_t OFF_KVT = OFF_KV + 491520;       // kvt [960][128]   bf16   245760
constexpr size_t OFF_F2  = OFF_KVT + 245760;      // f2  [512][128][16] bf16 2097152
constexpr size_t OFF_VT  = OFF_F2 + 2097152;      // vt  [512][960][16] bf16 15728640
constexpr size_t OFF_F1  = OFF_VT + 15728640;     // f1  [131072][128] bf16  33554432

// ---------------------------------------------------------------------------
__global__ void k_prep(const float* __restrict__ L, const float* __restrict__ R,
                       const float* __restrict__ W,
                       u16* __restrict__ Lt, u16* __restrict__ Rt, u16* __restrict__ Wb)
{
  int t = blockIdx.x*256 + threadIdx.x;
  if (t < 131072){                                   // Lt[j][k][i] = L[j][i][k]
    int j = t >> 12, k = (t >> 6) & 63, i = t & 63;
    Lt[t] = f2b(L[((size_t)j*64 + i)*64 + k]);
  } else if (t < 196608){                            // Rt[k][l][j] = R[k][j][l]
    int t2 = t - 131072;
    int k = t2 >> 10, l = (t2 >> 5) & 31, j = t2 & 31;
    Rt[t2] = f2b(R[((size_t)k*32 + j)*32 + l]);
  } else if (t < 204800){
    int t3 = t - 196608;
    Wb[t3] = f2b(W[t3]);
  }
}

// ---------------------------------------------------------------------------
// Fused stage 1.  One block = 16 rows (n), 512 threads (8 waves), 155 KB LDS.
// LDS: R1 @0      : SA [8][16][72] bf16 (stage)  then o_lds [16][2056] bf16
//      R2 @65792  : z_lds [64][16][40] bf16      then Qs_lds [256][72] bf16
//      R3 @148736 : Ks[16][64]f32, cos/sin[16][32]f32, stats[16][8], sumQ2[256], sumK2[16]
// ---------------------------------------------------------------------------
__launch_bounds__(512, 1)
__global__ void k_stage1(
    const float* __restrict__ data, const float* __restrict__ locs,
    const float* __restrict__ qsc, const float* __restrict__ qbi,
    const float* __restrict__ ksc, const float* __restrict__ kbi,
    const float* __restrict__ vsc, const float* __restrict__ vbi,
    const float* __restrict__ Wf,
    const u16* __restrict__ Lt, const u16* __restrict__ Rt, const u16* __restrict__ Wb,
    u16* __restrict__ f1g, u16* __restrict__ f2g, u16* __restrict__ vtg)
{
  extern __shared__ char smem[];
  u16*   SA      = (u16*)smem;                 // [8][16][72]
  u16*   o_lds   = (u16*)smem;                 // [16][2056]
  u16*   z_lds   = (u16*)(smem + 65792);       // [64][16][40]
  u16*   Qs_lds  = (u16*)(smem + 65792);       // [256][72]
  float* Ks_lds  = (float*)(smem + 148736);    // [16][64]
  float* cos_lds = (float*)(smem + 152832);    // [16][32]
  float* sin_lds = (float*)(smem + 154880);    // [16][32]
  float* stats   = (float*)(smem + 156928);    // [16][8]
  float* sumQ2   = (float*)(smem + 157440);    // [256]
  float* sumK2   = (float*)(smem + 158464);    // [16]

  const int tid  = threadIdx.x;
  const int wv   = tid >> 6;
  const int lane = tid & 63;
  const int g    = lane >> 4;
  const int fr   = lane & 15;
  const int nb   = blockIdx.x;
  const int n0   = nb * 16;

  // ---------- P1: z[n,j,k] = sum_i x[n,i,j] L[j,i,k]  (4 chunks of 8 j) ------
  for (int jc = 0; jc < 4; ++jc){
    #pragma unroll
    for (int pp = 0; pp < 2; ++pp){
      int p = tid*2 + pp;                 // (n,i) pair over 16*64
      int n = p >> 6, i = p & 63;
      const float* src = data + (size_t)(n0 + n)*2048 + i*32 + jc*8;
      float4 v0 = *(const float4*)(src);
      float4 v1 = *(const float4*)(src + 4);
      int base = n*72 + i;
      SA[0*1152 + base] = f2b(v0.x);  SA[1*1152 + base] = f2b(v0.y);
      SA[2*1152 + base] = f2b(v0.z);  SA[3*1152 + base] = f2b(v0.w);
      SA[4*1152 + base] = f2b(v1.x);  SA[5*1152 + base] = f2b(v1.y);
      SA[6*1152 + base] = f2b(v1.z);  SA[7*1152 + base] = f2b(v1.w);
    }
    __syncthreads();
    {
      int j = jc*8 + wv;                  // each wave owns one j
      bf16x8 a0 = *(const bf16x8*)(SA + wv*1152 + fr*72 + g*8);
      bf16x8 a1 = *(const bf16x8*)(SA + wv*1152 + fr*72 + 32 + g*8);
      #pragma unroll
      for (int kt = 0; kt < 4; ++kt){
        const u16* bp = Lt + ((size_t)j*64 + kt*16 + fr)*64 + g*8;
        bf16x8 b0 = *(const bf16x8*)(bp);
        bf16x8 b1 = *(const bf16x8*)(bp + 32);
        f32x4 acc = {0.f,0.f,0.f,0.f};
        acc = MFMA16(a0, b0, acc);
        acc = MFMA16(a1, b1, acc);
        int kcol = kt*16 + fr;            // D: col=lane&15 -> k ; rows = g*4+q
        u16* zp = z_lds + kcol*648 + j;
        zp[(g*4+0)*40] = f2b(acc[0]);
        zp[(g*4+1)*40] = f2b(acc[1]);
        zp[(g*4+2)*40] = f2b(acc[2]);
        zp[(g*4+3)*40] = f2b(acc[3]);
      }
    }
    __syncthreads();
  }

  // ---------- P2: o[n,k,l] = sum_j z[n,j,k] R[k,j,l], leaky-relu ------------
  {
    #pragma unroll
    for (int kk = 0; kk < 8; ++kk){
      int k = wv + 8*kk;
      bf16x8 a = *(const bf16x8*)(z_lds + k*648 + fr*40 + g*8);  // A[n=fr][j]
      #pragma unroll
      for (int lt = 0; lt < 2; ++lt){
        const u16* bp = Rt + ((size_t)k*32 + lt*16 + fr)*32 + g*8;
        bf16x8 b = *(const bf16x8*)(bp);
        f32x4 acc = {0.f,0.f,0.f,0.f};
        acc = MFMA16(a, b, acc);
        int col = k*32 + lt*16 + fr;
        #pragma unroll
        for (int q = 0; q < 4; ++q){
          float v = acc[q];
          v = v > 0.f ? v : 0.1f*v;
          o_lds[(g*4+q)*2056 + col] = f2b(v);
        }
      }
    }
  }
  __syncthreads();

  // ---------- P3: LN stats + rope tables ------------------------------------
  {
    int n = tid >> 5, s = tid & 31;
    float qs=0,qss=0,ks=0,kss=0,vs=0,vss=0;
    #pragma unroll
    for (int q = 0; q < 32; q += 8){
      bf16x8 h8 = *(const bf16x8*)(o_lds + n*2056 + s*32 + q);
      #pragma unroll
      for (int e = 0; e < 8; ++e){ float x = b2f((u16)h8[e]); qs += x; qss += x*x; }
    }
    { float x = b2f(o_lds[n*2056 + 1024 + s*2]);     ks += x; kss += x*x;
      x       = b2f(o_lds[n*2056 + 1024 + s*2 + 1]); ks += x; kss += x*x; }
    for (int q = 0; q < 30; ++q){
      float x = b2f(o_lds[n*2056 + 1088 + s*30 + q]); vs += x; vss += x*x;
    }
    #pragma unroll
    for (int m = 1; m < 32; m <<= 1){
      qs += __shfl_xor(qs, m, 32); qss += __shfl_xor(qss, m, 32);
      ks += __shfl_xor(ks, m, 32); kss += __shfl_xor(kss, m, 32);
      vs += __shfl_xor(vs, m, 32); vss += __shfl_xor(vss, m, 32);
    }
    if (s == 0){
      float mu;
      mu = qs*(1.f/1024.f); stats[n*8+0]=mu; stats[n*8+1]=rsqrtf(qss*(1.f/1024.f)-mu*mu + 1e-5f);
      mu = ks*(1.f/64.f);   stats[n*8+2]=mu; stats[n*8+3]=rsqrtf(kss*(1.f/64.f)  -mu*mu + 1e-5f);
      mu = vs*(1.f/960.f);  stats[n*8+4]=mu; stats[n*8+5]=rsqrtf(vss*(1.f/960.f) -mu*mu + 1e-5f);
    }
    float loc  = locs[n0 + n];
    float invf = (float)exp2(-(double)s * 0.4152410118609203);  // log2(1e4)/32
    float ang  = loc * invf;
    float sv, cv;
    sincosf(ang, &sv, &cv);
    cos_lds[n*32 + s] = cv;
    sin_lds[n*32 + s] = sv;
  }
  __syncthreads();

  // ---------- P4a: V normalize in place; K normalize+rope -> Ks -------------
  {
    int n = tid >> 5, s = tid & 31;
    float vmu = stats[n*8+4], vrs = stats[n*8+5];
    for (int q = 0; q < 30; ++q){
      int cc = s*30 + q;
      float x = b2f(o_lds[n*2056 + 1088 + cc]);
      x = (x - vmu)*vrs*vsc[cc] + vbi[cc];
      o_lds[n*2056 + 1088 + cc] = f2b(x);
    }
    if (s < 2){
      float kmu = stats[n*8+2], krs = stats[n*8+3];
      float a2 = 0.f;
      for (int d = s*16; d < s*16 + 16; ++d){
        float x1 = b2f(o_lds[n*2056 + 1024 + d]);
        float x2 = b2f(o_lds[n*2056 + 1024 + d + 32]);
        x1 = (x1 - kmu)*krs*ksc[d]    + kbi[d];
        x2 = (x2 - kmu)*krs*ksc[d+32] + kbi[d+32];
        float c = cos_lds[n*32+d], sn = sin_lds[n*32+d];
        float k1 = (c*x1 + sn*x2)*0.125f;       // sign=+1, /sqrt(64)
        float k2 = (c*x2 - sn*x1)*0.125f;
        Ks_lds[n*64 + d]      = k1;
        Ks_lds[n*64 + d + 32] = k2;
        a2 += k1*k1 + k2*k2;
      }
      a2 += __shfl_xor(a2, 1, 32);
      if (s == 0) sumK2[n] = a2;
    }
  }
  __syncthreads();

  // ---------- P4b: f2 = D*exp(A + B*wK - |Ks|^2) ; P4c: Qs -------------------
  {
    int n = tid >> 5, s = tid & 31;
    const float* kk = Ks_lds + n*64;
    float sk2 = sumK2[n];
    #pragma unroll
    for (int rr = 0; rr < 4; ++rr){
      int r = s*4 + rr;
      const float* wrow = Wf + r*64;
      float wk = 0.f;
      #pragma unroll
      for (int d = 0; d < 64; d += 4){
        float4 w4 = *(const float4*)(wrow + d);
        wk += kk[d]*w4.x + kk[d+1]*w4.y + kk[d+2]*w4.z + kk[d+3]*w4.w;
      }
      float f2v = DC_ * __expf(0.1f + BC_*wk - sk2);
      f2g[(size_t)nb*2048 + r*16 + n] = f2b(f2v);
    }
    if (s < 16){
      int h = s;
      float qmu = stats[n*8+0], qrs = stats[n*8+1];
      float a2 = 0.f;
      int row = n*16 + h;
      for (int d = 0; d < 32; ++d){
        float x1 = b2f(o_lds[n*2056 + h*64 + d]);
        float x2 = b2f(o_lds[n*2056 + h*64 + d + 32]);
        x1 = (x1 - qmu)*qrs*qsc[h*64+d]    + qbi[h*64+d];
        x2 = (x2 - qmu)*qrs*qsc[h*64+d+32] + qbi[h*64+d+32];
        float c = cos_lds[n*32+d], sn = sin_lds[n*32+d];
        float q1 = (c*x1 - sn*x2)*0.125f;       // sign=-1, /sqrt(64)
        float q2 = (c*x2 + sn*x1)*0.125f;
        Qs_lds[row*72 + d]      = f2b(q1);
        Qs_lds[row*72 + d + 32] = f2b(q2);
        a2 += q1*q1 + q2*q2;
      }
      sumQ2[row] = a2;
    }
  }
  __syncthreads();

  // ---------- P5: wQ = Qs @ W^T (MFMA) -> f1 --------------------------------
  {
    for (int rt = wv; rt < 16; rt += 8){
      bf16x8 a0 = *(const bf16x8*)(Qs_lds + (rt*16 + fr)*72 + g*8);
      bf16x8 a1 = *(const bf16x8*)(Qs_lds + (rt*16 + fr)*72 + 32 + g*8);
      #pragma unroll
      for (int ct = 0; ct < 8; ++ct){
        const u16* bp = Wb + (size_t)(ct*16 + fr)*64 + g*8;
        bf16x8 b0 = *(const bf16x8*)(bp);
        bf16x8 b1 = *(const bf16x8*)(bp + 32);
        f32x4 acc = {0.f,0.f,0.f,0.f};
        acc = MFMA16(a0, b0, acc);
        acc = MFMA16(a1, b1, acc);
        #pragma unroll
        for (int q = 0; q < 4; ++q){
          int lr = rt*16 + g*4 + q;
          float f1v = DC_ * __expf(0.1f + BC_*acc[q] - sumQ2[lr]);
          f1g[((size_t)nb*256 + lr)*128 + ct*16 + fr] = f2b(f1v);
        }
      }
    }
  }

  // ---------- P6: V_t (n-tiled-by-16, contiguous 32B per v) -----------------
  {
    for (int v = tid; v < 960; v += 512){
      u32 w[8];
      #pragma unroll
      for (int x = 0; x < 8; ++x){
        u32 lo = o_lds[(2*x  )*2056 + 1088 + v];
        u32 hi = o_lds[(2*x+1)*2056 + 1088 + v];
        w[x] = lo | (hi << 16);
      }
      u32* dst = (u32*)(vtg + (size_t)nb*15360 + (size_t)v*16);
      uint4 t0; t0.x=w[0]; t0.y=w[1]; t0.z=w[2]; t0.w=w[3];
      uint4 t1; t1.x=w[4]; t1.y=w[5]; t1.z=w[6]; t1.w=w[7];
      *(uint4*)(dst)     = t0;
      *(uint4*)(dst + 4) = t1;
    }
  }
}

// ---------------------------------------------------------------------------
// kv[r,v] = sum_n f2[n,r] V[n,v]   split-K MFMA + f32 atomics
// grid (60 vtiles, 16 ksplits), 256 thr
// ---------------------------------------------------------------------------
__launch_bounds__(256)
__global__ void k_kv(const u16* __restrict__ f2g, const u16* __restrict__ vtg,
                     float* __restrict__ kv)
{
  const int tid = threadIdx.x;
  const int wv = tid >> 6, lane = tid & 63;
  const int g = lane >> 4, fr = lane & 15;
  const int v0 = blockIdx.x * 16;
  const int nbase = blockIdx.y * 512;
  const int rt0 = wv*2, rt1 = wv*2 + 1;
  f32x4 acc0 = {0.f,0.f,0.f,0.f}, acc1 = {0.f,0.f,0.f,0.f};
  for (int ns = 0; ns < 16; ++ns){
    int nl  = nbase + ns*32 + g*8;
    int nbi = nl >> 4, nin = nl & 15;
    bf16x8 b  = *(const bf16x8*)(vtg + (size_t)nbi*15360 + (size_t)(v0 + fr)*16 + nin);
    bf16x8 a0 = *(const bf16x8*)(f2g + (size_t)nbi*2048  + (size_t)(rt0*16 + fr)*16 + nin);
    bf16x8 a1 = *(const bf16x8*)(f2g + (size_t)nbi*2048  + (size_t)(rt1*16 + fr)*16 + nin);
    acc0 = MFMA16(a0, b, acc0);
    acc1 = MFMA16(a1, b, acc1);
  }
  #pragma unroll
  for (int q = 0; q < 4; ++q){
    atomicAdd(&kv[(rt0*16 + g*4 + q)*960 + v0 + fr], acc0[q]);
    atomicAdd(&kv[(rt1*16 + g*4 + q)*960 + v0 + fr], acc1[q]);
  }
}

// ---------------------------------------------------------------------------
__global__ void k_kvt(const float* __restrict__ kv, u16* __restrict__ kvt)
{
  int t = blockIdx.x*256 + threadIdx.x;
  if (t < 122880){
    int r = t / 960, v = t - r*960;
    kvt[v*128 + r] = f2b(kv[t]);
  }
}

// ---------------------------------------------------------------------------
// O[(n,h), v] = f1 @ kv   M=131072 K=128 N=960, write-bound.
// block = 256 thr (4 waves x 32 rows), grid 1024.
// ---------------------------------------------------------------------------
__launch_bounds__(256, 2)
__global__ void k_out(const u16* __restrict__ f1g, const u16* __restrict__ kvt,
                      float* __restrict__ out)
{
  const int tid = threadIdx.x;
  const int wv = tid >> 6, lane = tid & 63;
  const int c = lane & 31, gg = lane >> 5;
  const size_t rowbase = (size_t)blockIdx.x*128 + (size_t)wv*32;
  bf16x8 a[8];
  const u16* ap = f1g + (rowbase + c)*128 + gg*8;
  #pragma unroll
  for (int ks = 0; ks < 8; ++ks) a[ks] = *(const bf16x8*)(ap + ks*16);
  for (int vt = 0; vt < 30; ++vt){
    f32x16 acc = {0.f,0.f,0.f,0.f, 0.f,0.f,0.f,0.f, 0.f,0.f,0.f,0.f, 0.f,0.f,0.f,0.f};
    #pragma unroll
    for (int ks = 0; ks < 8; ++ks){
      bf16x8 b = *(const bf16x8*)(kvt + (size_t)(vt*32 + c)*128 + ks*16 + gg*8);
      acc = MFMA32(a[ks], b, acc);
    }
    #pragma unroll
    for (int q = 0; q < 16; ++q){
      int rr = (q & 3) + 8*(q >> 2) + 4*gg;
      out[(rowbase + rr)*960 + vt*32 + c] = acc[q];
    }
  }
}

// ---------------------------------------------------------------------------
extern "C" void kernel_launch(void* const* d_in, const int* in_sizes, int n_in,
                              void* d_out, int out_size, void* d_ws, size_t ws_size,
                              hipStream_t stream)
{
  (void)in_sizes; (void)n_in; (void)out_size; (void)ws_size;
  const float* data = (const float*)d_in[0];
  const float* locs = (const float*)d_in[1];
  const float* L    = (const float*)d_in[2];
  const float* R    = (const float*)d_in[3];
  const float* qsc  = (const float*)d_in[4];
  const float* qbi  = (const float*)d_in[5];
  const float* ksc  = (const float*)d_in[6];
  const float* kbi  = (const float*)d_in[7];
  const float* vsc  = (const float*)d_in[8];
  const float* vbi  = (const float*)d_in[9];
  const float* W    = (const float*)d_in[10];

  char* ws = (char*)d_ws;
  u16*   Lt  = (u16*)(ws + OFF_LT);
  u16*   Rt  = (u16*)(ws + OFF_RT);
  u16*   Wb  = (u16*)(ws + OFF_WB);
  float* kv  = (float*)(ws + OFF_KV);
  u16*   kvt = (u16*)(ws + OFF_KVT);
  u16*   f2g = (u16*)(ws + OFF_F2);
  u16*   vtg = (u16*)(ws + OFF_VT);
  u16*   f1g = (u16*)(ws + OFF_F1);

  // >64KB dynamic LDS opt-in (host-side, idempotent; same work every call)
  hipFuncSetAttribute((const void*)k_stage1,
                      hipFuncAttributeMaxDynamicSharedMemorySize, 158528);

  hipMemsetAsync(kv, 0, 122880*sizeof(float), stream);
  k_prep<<<800, 256, 0, stream>>>(L, R, W, Lt, Rt, Wb);
  k_stage1<<<512, 512, 158528, stream>>>(data, locs, qsc, qbi, ksc, kbi, vsc, vbi,
                                         W, Lt, Rt, Wb, f1g, f2g, vtg);
  k_kv<<<dim3(60,16), 256, 0, stream>>>(f2g, vtg, kv);
  k_kvt<<<480, 256, 0, stream>>>(kv, kvt);
  k_out<<<1024, 256, 0, stream>>>(f1g, kvt, (float*)d_out);
}